// Round 10
// baseline (551.769 us; speedup 1.0000x reference)
//
#include <hip/hip_runtime.h>
#include <hip/hip_bf16.h>

static constexpr int N_NODES = 100000;
static constexpr int N_EDGES = 1600000;
static constexpr int N_GRAPH = 2048;
static constexpr float BN_EPS_C = 1e-5f;

// bucket-sort CSR build parameters
static constexpr int BUCK_SHIFT = 9;                         // 512 nodes per bucket
static constexpr int NB_BUCK = (N_NODES + 511) >> 9;         // 196
static constexpr int PART_B = 256;                           // partition blocks
static constexpr int CHUNK = N_EDGES / PART_B;               // 6250 (exact)
static constexpr int NTOT = NB_BUCK * PART_B;                // 50176 = 49*1024 (exact)
static constexpr int NSLOT = 8;                              // BN-stats atomic slots

typedef unsigned int uint;
typedef unsigned short ushort;

// ---------------- bf16 helpers (RNE pack, shift unpack) ----------------

__device__ inline uint pk2(float a, float b) {
    uint ua = __float_as_uint(a), ub = __float_as_uint(b);
    ua = (ua + 0x7fffu + ((ua >> 16) & 1u)) >> 16;
    ub = (ub + 0x7fffu + ((ub >> 16) & 1u)) >> 16;
    return ua | (ub << 16);
}
__device__ inline float b2f_lo(uint u) { return __uint_as_float(u << 16); }
__device__ inline float b2f_hi(uint u) { return __uint_as_float(u & 0xffff0000u); }

__device__ inline void unpack8(uint4 v, float* f) {
    f[0] = b2f_lo(v.x); f[1] = b2f_hi(v.x);
    f[2] = b2f_lo(v.y); f[3] = b2f_hi(v.y);
    f[4] = b2f_lo(v.z); f[5] = b2f_hi(v.z);
    f[6] = b2f_lo(v.w); f[7] = b2f_hi(v.w);
}

// ---------------- CSR build: two-level bucket sort, LDS atomics only ----------------

__global__ __launch_bounds__(256) void k_bcount(const int* __restrict__ dst, int* __restrict__ cnt) {
    __shared__ int h[NB_BUCK];
    int blk = blockIdx.x, tid = threadIdx.x;
    for (int i = tid; i < NB_BUCK; i += 256) h[i] = 0;
    __syncthreads();
    int base = blk * CHUNK;
    for (int e = base + tid; e < base + CHUNK; e += 256) {
        int d = __builtin_nontemporal_load(&dst[e]);
        atomicAdd(&h[d >> BUCK_SHIFT], 1);
    }
    __syncthreads();
    for (int i = tid; i < NB_BUCK; i += 256) cnt[i * PART_B + blk] = h[i];
}

__global__ __launch_bounds__(256) void k_scan_partial2(const int* __restrict__ v, int* __restrict__ part, int n) {
    __shared__ int sw[4];
    int b = blockIdx.x, tid = threadIdx.x;
    int base = b * 1024;
    int s = 0;
#pragma unroll
    for (int r = 0; r < 4; ++r) {
        int i = base + r * 256 + tid;
        if (i < n) s += v[i];
    }
#pragma unroll
    for (int off = 32; off > 0; off >>= 1) s += __shfl_down(s, off);
    if ((tid & 63) == 0) sw[tid >> 6] = s;
    __syncthreads();
    if (tid == 0) part[b] = sw[0] + sw[1] + sw[2] + sw[3];
}

__global__ __launch_bounds__(256) void k_scan_offsets2(int* __restrict__ part, int nb, int* __restrict__ bstart) {
    __shared__ int sh[256];
    int tid = threadIdx.x;
    sh[tid] = (tid < nb) ? part[tid] : 0;
    __syncthreads();
    if (tid == 0) {
        int run = 0;
        for (int i = 0; i < nb; ++i) { int v = sh[i]; sh[i] = run; run += v; }
        bstart[NB_BUCK] = run;
    }
    __syncthreads();
    if (tid < nb) part[tid] = sh[tid];
}

__global__ __launch_bounds__(256) void k_scan_final2(int* __restrict__ cnt, const int* __restrict__ part,
                                                     int* __restrict__ bstart, int n) {
    __shared__ int wsum[4];
    int b = blockIdx.x, tid = threadIdx.x;
    int lane = tid & 63, w = tid >> 6;
    int base = b * 1024 + tid * 4;
    int v[4];
#pragma unroll
    for (int r = 0; r < 4; ++r) {
        int i = base + r;
        v[r] = (i < n) ? cnt[i] : 0;
    }
    int tsum = v[0] + v[1] + v[2] + v[3];
    int inc = tsum;
#pragma unroll
    for (int off = 1; off < 64; off <<= 1) {
        int t = __shfl_up(inc, off);
        if (lane >= off) inc += t;
    }
    if (lane == 63) wsum[w] = inc;
    __syncthreads();
    int woff = 0;
    for (int ww = 0; ww < w; ++ww) woff += wsum[ww];
    int run = part[b] + woff + (inc - tsum);
#pragma unroll
    for (int r = 0; r < 4; ++r) {
        int idx = base + r;
        if (idx < n) {
            int c = v[r];
            cnt[idx] = run;
            if ((idx & (PART_B - 1)) == 0) bstart[idx / PART_B] = run;
            run += c;
        }
    }
}

__global__ __launch_bounds__(256) void k_bpart(const int* __restrict__ src, const int* __restrict__ dst,
                                               const int* __restrict__ cnt, int2* __restrict__ ebuf) {
    __shared__ int cur[NB_BUCK];
    int blk = blockIdx.x, tid = threadIdx.x;
    for (int i = tid; i < NB_BUCK; i += 256) cur[i] = cnt[i * PART_B + blk];
    __syncthreads();
    int base = blk * CHUNK;
    for (int e = base + tid; e < base + CHUNK; e += 256) {
        int d = __builtin_nontemporal_load(&dst[e]);
        int s = __builtin_nontemporal_load(&src[e]);
        int p = atomicAdd(&cur[d >> BUCK_SHIFT], 1);
        ebuf[p] = make_int2(d, s);
    }
}

// Per-bucket fine CSR + within-bucket degree sort -> perm (wave load balance).
__global__ __launch_bounds__(256) void k_bfine(const int2* __restrict__ ebuf, const int* __restrict__ bstart,
                                               int* __restrict__ row_ptr, int* __restrict__ row_end,
                                               int* __restrict__ ssrc, int* __restrict__ perm) {
    __shared__ int fh[512];
    __shared__ int wsum[4];
    __shared__ int dh[64];
    __shared__ int dcur[64];
    int b = blockIdx.x, tid = threadIdx.x;
    int n0 = b << BUCK_SHIFT;
    int e0 = bstart[b], e1 = bstart[b + 1];
    fh[tid] = 0; fh[tid + 256] = 0;
    if (tid < 64) dh[tid] = 0;
    __syncthreads();
    for (int e = e0 + tid; e < e1; e += 256)
        atomicAdd(&fh[ebuf[e].x - n0], 1);
    __syncthreads();
    int a0 = fh[2 * tid], a1 = fh[2 * tid + 1];
    int node0 = n0 + 2 * tid, node1 = node0 + 1;
    int b0 = a0 < 63 ? a0 : 63, b1 = a1 < 63 ? a1 : 63;
    if (node0 < N_NODES) atomicAdd(&dh[b0], 1);
    if (node1 < N_NODES) atomicAdd(&dh[b1], 1);
    int s = a0 + a1;
    int lane = tid & 63, w = tid >> 6;
    int inc = s;
#pragma unroll
    for (int off = 1; off < 64; off <<= 1) {
        int t = __shfl_up(inc, off);
        if (lane >= off) inc += t;
    }
    if (lane == 63) wsum[w] = inc;
    __syncthreads();   // wsum ready; dh atomics done
    // exclusive scan of dh by wave 0 -> dcur = bucket-base + offset
    if (tid < 64) {
        int dv = dh[tid];
        int dinc = dv;
#pragma unroll
        for (int off = 1; off < 64; off <<= 1) {
            int t = __shfl_up(dinc, off);
            if (tid >= off) dinc += t;
        }
        dcur[tid] = n0 + (dinc - dv);
    }
    int woff = 0;
    for (int ww = 0; ww < w; ++ww) woff += wsum[ww];
    int excl = woff + inc - s;
    int p0 = excl, p1 = excl + a0;
    if (node0 < N_NODES) { row_ptr[node0] = e0 + p0; row_end[node0] = e0 + p0 + a0; }
    if (node1 < N_NODES) { row_ptr[node1] = e0 + p1; row_end[node1] = e0 + p1 + a1; }
    fh[2 * tid] = p0; fh[2 * tid + 1] = p1;
    __syncthreads();   // cursors + dcur ready
    if (node0 < N_NODES) { int p = atomicAdd(&dcur[b0], 1); perm[p] = node0; }
    if (node1 < N_NODES) { int p = atomicAdd(&dcur[b1], 1); perm[p] = node1; }
    for (int e = e0 + tid; e < e1; e += 256) {
        int2 v = ebuf[e];
        int p = atomicAdd(&fh[v.x - n0], 1);
        ssrc[e0 + p] = v.y;
    }
}

// ---------------- layer-1 weight commute: y = x @ W1a ----------------

__global__ __launch_bounds__(256) void k_xw1(const float* __restrict__ x, const float* __restrict__ Wa,
                                             ushort* __restrict__ y) {
    __shared__ float sWa[2048];   // 64x32, col XOR-swizzled by ((r>>4)&3)<<2
    int tid = threadIdx.x;
    for (int i = tid; i < 2048; i += 256) {
        int r = i >> 5, c = i & 31;
        sWa[(r << 5) + (c ^ (((r >> 4) & 3) << 2))] = Wa[i];
    }
    __syncthreads();
    int idx = blockIdx.x * 256 + tid;
    int node = idx >> 2;
    int sl = idx & 3;
    int k0 = sl * 16;
    bool active = node < N_NODES;

    float xv[16];
    if (active) {
        const float* xr = x + (size_t)node * 64 + k0;
        *(float4*)(xv + 0)  = *(const float4*)(xr + 0);
        *(float4*)(xv + 4)  = *(const float4*)(xr + 4);
        *(float4*)(xv + 8)  = *(const float4*)(xr + 8);
        *(float4*)(xv + 12) = *(const float4*)(xr + 12);
    } else {
#pragma unroll
        for (int j = 0; j < 16; ++j) xv[j] = 0.f;
    }

    float pj[32];
#pragma unroll
    for (int j = 0; j < 32; ++j) pj[j] = 0.f;
    int sw = sl << 2;
#pragma unroll
    for (int kk = 0; kk < 16; ++kk) {
        float a = xv[kk];
        const float* rb = sWa + ((k0 + kk) << 5);
#pragma unroll
        for (int j4 = 0; j4 < 8; ++j4) {
            int jo = j4 << 2;
            float4 wv = *(const float4*)(rb + (jo ^ sw));
            pj[jo + 0] = fmaf(a, wv.x, pj[jo + 0]);
            pj[jo + 1] = fmaf(a, wv.y, pj[jo + 1]);
            pj[jo + 2] = fmaf(a, wv.z, pj[jo + 2]);
            pj[jo + 3] = fmaf(a, wv.w, pj[jo + 3]);
        }
    }
#pragma unroll
    for (int j = 0; j < 32; ++j) {
        pj[j] += __shfl_xor(pj[j], 1);
        pj[j] += __shfl_xor(pj[j], 2);
    }
    if (active && sl == 0) {
        uint pk[16];
#pragma unroll
        for (int j = 0; j < 16; ++j) pk[j] = pk2(pj[2 * j], pj[2 * j + 1]);
        uint4* yp = (uint4*)(y + (size_t)node * 32);
        yp[0] = make_uint4(pk[0], pk[1], pk[2], pk[3]);
        yp[1] = make_uint4(pk[4], pk[5], pk[6], pk[7]);
        yp[2] = make_uint4(pk[8], pk[9], pk[10], pk[11]);
        yp[3] = make_uint4(pk[12], pk[13], pk[14], pk[15]);
    }
}

// ---------------- fused layer 1: gather(y) + bias/relu + Wb GEMM + BN-stats ----------------
// 4 lanes/node, node order from degree-sorted perm (wave load balance).

__global__ __launch_bounds__(256) void k_fused1y(const ushort* __restrict__ y,
                                                 const int* __restrict__ row_ptr, const int* __restrict__ row_end,
                                                 const int* __restrict__ ssrc, const int* __restrict__ perm,
                                                 const float* __restrict__ ba,
                                                 const float* __restrict__ Wb, const float* __restrict__ bb,
                                                 ushort* __restrict__ uout, float* __restrict__ stats_out) {
    __shared__ float sWb[1024];
    __shared__ float sba[32];
    __shared__ float sbb[32];
    __shared__ float bstats[64];
    __shared__ float tile[64][36];
    int tid = threadIdx.x;
    for (int i = tid; i < 1024; i += 256) sWb[i] = Wb[i];
    if (tid < 32) { sba[tid] = ba[tid]; sbb[tid] = bb[tid]; }
    if (tid < 64) bstats[tid] = 0.f;
    __syncthreads();

    int idx = blockIdx.x * 256 + tid;
    int nid = idx >> 2;
    int sl = idx & 3;
    int f8 = sl * 8;
    int nloc = tid >> 2;
    bool active = nid < N_NODES;
    int node = active ? perm[nid] : 0;

    float acc[8] = {0.f, 0.f, 0.f, 0.f, 0.f, 0.f, 0.f, 0.f};
    if (active) {
        unpack8(*(const uint4*)(y + (size_t)node * 32 + f8), acc);
        int e = row_ptr[node], e1 = row_end[node];
        float v[8];
        for (; e + 4 <= e1; e += 4) {
            int s0 = ssrc[e], s1 = ssrc[e + 1], s2 = ssrc[e + 2], s3 = ssrc[e + 3];
            uint4 va = *(const uint4*)(y + (size_t)s0 * 32 + f8);
            uint4 vb = *(const uint4*)(y + (size_t)s1 * 32 + f8);
            uint4 vc = *(const uint4*)(y + (size_t)s2 * 32 + f8);
            uint4 vd = *(const uint4*)(y + (size_t)s3 * 32 + f8);
            unpack8(va, v);
#pragma unroll
            for (int j = 0; j < 8; ++j) acc[j] += v[j];
            unpack8(vb, v);
#pragma unroll
            for (int j = 0; j < 8; ++j) acc[j] += v[j];
            unpack8(vc, v);
#pragma unroll
            for (int j = 0; j < 8; ++j) acc[j] += v[j];
            unpack8(vd, v);
#pragma unroll
            for (int j = 0; j < 8; ++j) acc[j] += v[j];
        }
        for (; e < e1; ++e) {
            int s = ssrc[e];
            unpack8(*(const uint4*)(y + (size_t)s * 32 + f8), v);
#pragma unroll
            for (int j = 0; j < 8; ++j) acc[j] += v[j];
        }
    }

    float h8[8];
#pragma unroll
    for (int j = 0; j < 8; ++j) h8[j] = fmaxf(acc[j] + sba[f8 + j], 0.f);
    *(float4*)&tile[nloc][f8] = make_float4(h8[0], h8[1], h8[2], h8[3]);
    *(float4*)&tile[nloc][f8 + 4] = make_float4(h8[4], h8[5], h8[6], h8[7]);
    __syncthreads();

    float uu[8];
#pragma unroll
    for (int j = 0; j < 8; ++j) uu[j] = sbb[f8 + j];
#pragma unroll
    for (int k4 = 0; k4 < 8; ++k4) {
        float4 hv = *(const float4*)&tile[nloc][k4 * 4];
        float hvv[4] = {hv.x, hv.y, hv.z, hv.w};
#pragma unroll
        for (int m = 0; m < 4; ++m) {
            int k = k4 * 4 + m;
            float a = hvv[m];
            const float4* wr = (const float4*)(sWb + k * 32 + f8);
            float4 w0 = wr[0], w1 = wr[1];
            uu[0] = fmaf(a, w0.x, uu[0]);
            uu[1] = fmaf(a, w0.y, uu[1]);
            uu[2] = fmaf(a, w0.z, uu[2]);
            uu[3] = fmaf(a, w0.w, uu[3]);
            uu[4] = fmaf(a, w1.x, uu[4]);
            uu[5] = fmaf(a, w1.y, uu[5]);
            uu[6] = fmaf(a, w1.z, uu[6]);
            uu[7] = fmaf(a, w1.w, uu[7]);
        }
    }

    if (active) {
        uint4 pkv = make_uint4(pk2(uu[0], uu[1]), pk2(uu[2], uu[3]), pk2(uu[4], uu[5]), pk2(uu[6], uu[7]));
        *(uint4*)(uout + (size_t)node * 32 + f8) = pkv;
    } else {
#pragma unroll
        for (int j = 0; j < 8; ++j) uu[j] = 0.f;
    }

#pragma unroll
    for (int j = 0; j < 8; ++j) {
        float v = uu[j];
        float v2 = v * v;
        v += __shfl_xor(v, 4);  v2 += __shfl_xor(v2, 4);
        v += __shfl_xor(v, 8);  v2 += __shfl_xor(v2, 8);
        v += __shfl_xor(v, 16); v2 += __shfl_xor(v2, 16);
        v += __shfl_xor(v, 32); v2 += __shfl_xor(v2, 32);
        if ((tid & 63) < 4) {
            atomicAdd(&bstats[f8 + j], v);
            atomicAdd(&bstats[32 + f8 + j], v2);
        }
    }
    __syncthreads();
    if (tid < 64) atomicAdd(&stats_out[(blockIdx.x & (NSLOT - 1)) * 64 + tid], bstats[tid]);
}

// ---------------- fused layers 2-5: BN+gather(u) + MLP + BN-stats ----------------
// 4 lanes/node, degree-sorted perm order.

__global__ __launch_bounds__(256) void k_fused(const ushort* __restrict__ uin, ushort* __restrict__ uout,
                                               const float* __restrict__ stats_in, float* __restrict__ stats_out,
                                               const float* __restrict__ bng, const float* __restrict__ bnb,
                                               const int* __restrict__ row_ptr, const int* __restrict__ row_end,
                                               const int* __restrict__ ssrc, const int* __restrict__ perm,
                                               const float* __restrict__ Wa, const float* __restrict__ ba,
                                               const float* __restrict__ Wb, const float* __restrict__ bb) {
    __shared__ float sWa[1024];   // 32x32, col XOR-swizzled by ((r>>3)&3)<<2
    __shared__ float sWb[1024];
    __shared__ float sba[32];
    __shared__ float sbb[32];
    __shared__ float bstats[64];
    int tid = threadIdx.x;
    for (int i = tid; i < 1024; i += 256) {
        int r = i >> 5, c = i & 31;
        sWa[(r << 5) + (c ^ (((r >> 3) & 3) << 2))] = Wa[i];
        sWb[i] = Wb[i];
    }
    if (tid < 32) { sba[tid] = ba[tid]; sbb[tid] = bb[tid]; }
    if (tid < 64) bstats[tid] = 0.f;
    __syncthreads();

    int idx = blockIdx.x * 256 + tid;
    int nid = idx >> 2;
    int sl = idx & 3;
    int f8 = sl * 8;
    bool active = nid < N_NODES;
    int node = active ? perm[nid] : 0;

    const float inv = 1.0f / (float)N_NODES;
    float sc[8], sh[8];
    {
        float s1[8] = {0,0,0,0,0,0,0,0}, s2[8] = {0,0,0,0,0,0,0,0};
        for (int s = 0; s < NSLOT; ++s) {
            const float* sp = stats_in + s * 64;
            float4 a = *(const float4*)(sp + f8);
            float4 b = *(const float4*)(sp + f8 + 4);
            float4 c = *(const float4*)(sp + 32 + f8);
            float4 d = *(const float4*)(sp + 36 + f8);
            s1[0] += a.x; s1[1] += a.y; s1[2] += a.z; s1[3] += a.w;
            s1[4] += b.x; s1[5] += b.y; s1[6] += b.z; s1[7] += b.w;
            s2[0] += c.x; s2[1] += c.y; s2[2] += c.z; s2[3] += c.w;
            s2[4] += d.x; s2[5] += d.y; s2[6] += d.z; s2[7] += d.w;
        }
        float g[8], b[8];
        *(float4*)g = *(const float4*)(bng + f8); *(float4*)(g + 4) = *(const float4*)(bng + f8 + 4);
        *(float4*)b = *(const float4*)(bnb + f8); *(float4*)(b + 4) = *(const float4*)(bnb + f8 + 4);
#pragma unroll
        for (int j = 0; j < 8; ++j) {
            float mu = s1[j] * inv;
            sc[j] = rsqrtf(s2[j] * inv - mu * mu + BN_EPS_C) * g[j];
            sh[j] = b[j] - mu * sc[j];
        }
    }

    float acc[8] = {0.f, 0.f, 0.f, 0.f, 0.f, 0.f, 0.f, 0.f};
    if (active) {
        float v[8];
        unpack8(*(const uint4*)(uin + (size_t)node * 32 + f8), v);
#pragma unroll
        for (int j = 0; j < 8; ++j) acc[j] = fmaxf(fmaf(v[j], sc[j], sh[j]), 0.f);
        int e = row_ptr[node], e1 = row_end[node];
        for (; e + 4 <= e1; e += 4) {
            int s0 = ssrc[e], s1 = ssrc[e + 1], s2 = ssrc[e + 2], s3 = ssrc[e + 3];
            uint4 va = *(const uint4*)(uin + (size_t)s0 * 32 + f8);
            uint4 vb = *(const uint4*)(uin + (size_t)s1 * 32 + f8);
            uint4 vc = *(const uint4*)(uin + (size_t)s2 * 32 + f8);
            uint4 vd = *(const uint4*)(uin + (size_t)s3 * 32 + f8);
            unpack8(va, v);
#pragma unroll
            for (int j = 0; j < 8; ++j) acc[j] += fmaxf(fmaf(v[j], sc[j], sh[j]), 0.f);
            unpack8(vb, v);
#pragma unroll
            for (int j = 0; j < 8; ++j) acc[j] += fmaxf(fmaf(v[j], sc[j], sh[j]), 0.f);
            unpack8(vc, v);
#pragma unroll
            for (int j = 0; j < 8; ++j) acc[j] += fmaxf(fmaf(v[j], sc[j], sh[j]), 0.f);
            unpack8(vd, v);
#pragma unroll
            for (int j = 0; j < 8; ++j) acc[j] += fmaxf(fmaf(v[j], sc[j], sh[j]), 0.f);
        }
        for (; e < e1; ++e) {
            int s = ssrc[e];
            unpack8(*(const uint4*)(uin + (size_t)s * 32 + f8), v);
#pragma unroll
            for (int j = 0; j < 8; ++j) acc[j] += fmaxf(fmaf(v[j], sc[j], sh[j]), 0.f);
        }
    }

    // phase 1 partials; read at (jo^sw), accumulate at original column jo
    float pj[32];
#pragma unroll
    for (int j = 0; j < 32; ++j) pj[j] = 0.f;
    int sw = sl << 2;
#pragma unroll
    for (int kk = 0; kk < 8; ++kk) {
        float a = acc[kk];
        const float* rb = sWa + ((f8 + kk) << 5);
#pragma unroll
        for (int j4 = 0; j4 < 8; ++j4) {
            int jo = j4 << 2;
            float4 wv = *(const float4*)(rb + (jo ^ sw));
            pj[jo + 0] = fmaf(a, wv.x, pj[jo + 0]);
            pj[jo + 1] = fmaf(a, wv.y, pj[jo + 1]);
            pj[jo + 2] = fmaf(a, wv.z, pj[jo + 2]);
            pj[jo + 3] = fmaf(a, wv.w, pj[jo + 3]);
        }
    }
#pragma unroll
    for (int j = 0; j < 32; ++j) {
        pj[j] += __shfl_xor(pj[j], 1);
        pj[j] += __shfl_xor(pj[j], 2);
        pj[j] = fmaxf(pj[j] + sba[j], 0.f);
    }

    float uu[8];
#pragma unroll
    for (int j = 0; j < 8; ++j) uu[j] = sbb[f8 + j];
#pragma unroll
    for (int k = 0; k < 32; ++k) {
        float a = pj[k];
        const float4* wr = (const float4*)(sWb + k * 32 + f8);
        float4 w0 = wr[0], w1 = wr[1];
        uu[0] = fmaf(a, w0.x, uu[0]);
        uu[1] = fmaf(a, w0.y, uu[1]);
        uu[2] = fmaf(a, w0.z, uu[2]);
        uu[3] = fmaf(a, w0.w, uu[3]);
        uu[4] = fmaf(a, w1.x, uu[4]);
        uu[5] = fmaf(a, w1.y, uu[5]);
        uu[6] = fmaf(a, w1.z, uu[6]);
        uu[7] = fmaf(a, w1.w, uu[7]);
    }

    if (active) {
        uint4 pkv = make_uint4(pk2(uu[0], uu[1]), pk2(uu[2], uu[3]), pk2(uu[4], uu[5]), pk2(uu[6], uu[7]));
        *(uint4*)(uout + (size_t)node * 32 + f8) = pkv;
    } else {
#pragma unroll
        for (int j = 0; j < 8; ++j) uu[j] = 0.f;
    }

#pragma unroll
    for (int j = 0; j < 8; ++j) {
        float v = uu[j];
        float v2 = v * v;
        v += __shfl_xor(v, 4);  v2 += __shfl_xor(v2, 4);
        v += __shfl_xor(v, 8);  v2 += __shfl_xor(v2, 8);
        v += __shfl_xor(v, 16); v2 += __shfl_xor(v2, 16);
        v += __shfl_xor(v, 32); v2 += __shfl_xor(v2, 32);
        if ((tid & 63) < 4) {
            atomicAdd(&bstats[f8 + j], v);
            atomicAdd(&bstats[32 + f8 + j], v2);
        }
    }
    __syncthreads();
    if (tid < 64) atomicAdd(&stats_out[(blockIdx.x & (NSLOT - 1)) * 64 + tid], bstats[tid]);
}

// ---------------- layer-5 BN + graph pooling (segmented over sorted batch) ----------------

__global__ __launch_bounds__(256) void k_bn_pool(const ushort* __restrict__ u, const float* __restrict__ stats,
                                                 const float* __restrict__ bng, const float* __restrict__ bnb,
                                                 const int* __restrict__ batch, float* __restrict__ pooled) {
    const int CH = 128;
    int wid = (blockIdx.x * 256 + threadIdx.x) >> 6;
    int lane = threadIdx.x & 63;
    int f = lane & 31, par = lane >> 5;
    int n0 = wid * CH;
    if (n0 >= N_NODES) return;
    int n1 = n0 + CH; if (n1 > N_NODES) n1 = N_NODES;
    const float inv = 1.0f / (float)N_NODES;
    float sv = 0.f, sq = 0.f;
    for (int s = 0; s < NSLOT; ++s) { sv += stats[s * 64 + f]; sq += stats[s * 64 + 32 + f]; }
    float mu = sv * inv;
    float var = sq * inv - mu * mu;
    float sc = rsqrtf(var + BN_EPS_C) * bng[f];
    float sh = bnb[f] - mu * sc;
    float acc = 0.f;
    int curg = -1;
    for (int n = n0 + par; n < n1; n += 2) {
        int g = batch[n];
        if (g != curg) {
            if (curg >= 0) atomicAdd(&pooled[(size_t)curg * 32 + f], acc);
            acc = 0.f; curg = g;
        }
        float v = b2f_lo((uint)u[(size_t)n * 32 + f]);
        acc += fmaxf(fmaf(v, sc, sh), 0.f);
    }
    if (curg >= 0) atomicAdd(&pooled[(size_t)curg * 32 + f], acc);
}

// ---------------- head GEMMs ----------------

#define GEMM_COMPUTE_16()                                                      \
    _Pragma("unroll")                                                          \
    for (int k = 0; k < 16; ++k) {                                             \
        float4 a4 = *(const float4*)&As[k][ty * 4];                            \
        float4 b4 = *(const float4*)&Bs[k][tx * 4];                            \
        acc[0][0] = fmaf(a4.x, b4.x, acc[0][0]);                               \
        acc[0][1] = fmaf(a4.x, b4.y, acc[0][1]);                               \
        acc[0][2] = fmaf(a4.x, b4.z, acc[0][2]);                               \
        acc[0][3] = fmaf(a4.x, b4.w, acc[0][3]);                               \
        acc[1][0] = fmaf(a4.y, b4.x, acc[1][0]);                               \
        acc[1][1] = fmaf(a4.y, b4.y, acc[1][1]);                               \
        acc[1][2] = fmaf(a4.y, b4.z, acc[1][2]);                               \
        acc[1][3] = fmaf(a4.y, b4.w, acc[1][3]);                               \
        acc[2][0] = fmaf(a4.z, b4.x, acc[2][0]);                               \
        acc[2][1] = fmaf(a4.z, b4.y, acc[2][1]);                               \
        acc[2][2] = fmaf(a4.z, b4.z, acc[2][2]);                               \
        acc[2][3] = fmaf(a4.z, b4.w, acc[2][3]);                               \
        acc[3][0] = fmaf(a4.w, b4.x, acc[3][0]);                               \
        acc[3][1] = fmaf(a4.w, b4.y, acc[3][1]);                               \
        acc[3][2] = fmaf(a4.w, b4.z, acc[3][2]);                               \
        acc[3][3] = fmaf(a4.w, b4.w, acc[3][3]);                               \
    }

__global__ __launch_bounds__(256) void k_gemm_f(const float* __restrict__ A, const float* __restrict__ B,
                                                const float* __restrict__ bias, float* __restrict__ C,
                                                int Nc, int K, int ldc, int do_relu) {
    __shared__ float As[16][64];
    __shared__ float Bs[16][64];
    int tid = threadIdx.x;
    int tx = tid & 15, ty = tid >> 4;
    int bm = blockIdx.x * 64, bn = blockIdx.y * 64;
    float acc[4][4] = {{0.f}};
    int am = tid >> 2;
    int ak = (tid & 3) * 4;
    int bk = tid >> 4;
    int bn4 = (tid & 15) * 4;
    const float* Ap = A + (size_t)(bm + am) * K + ak;
    const float* Bp = B + (size_t)bk * Nc + bn + bn4;
    float4 av = *(const float4*)Ap;
    float4 bv = *(const float4*)Bp;
    for (int k0 = 0; k0 < K; k0 += 16) {
        As[ak + 0][am] = av.x;
        As[ak + 1][am] = av.y;
        As[ak + 2][am] = av.z;
        As[ak + 3][am] = av.w;
        *(float4*)&Bs[bk][bn4] = bv;
        __syncthreads();
        if (k0 + 16 < K) {
            av = *(const float4*)(Ap + k0 + 16);
            bv = *(const float4*)(Bp + (size_t)(k0 + 16) * Nc);
        }
        GEMM_COMPUTE_16()
        __syncthreads();
    }
    float4 bi = *(const float4*)(bias + bn + tx * 4);
#pragma unroll
    for (int i = 0; i < 4; ++i) {
        float4 v;
        v.x = acc[i][0] + bi.x;
        v.y = acc[i][1] + bi.y;
        v.z = acc[i][2] + bi.z;
        v.w = acc[i][3] + bi.w;
        if (do_relu) {
            v.x = fmaxf(v.x, 0.f); v.y = fmaxf(v.y, 0.f);
            v.z = fmaxf(v.z, 0.f); v.w = fmaxf(v.w, 0.f);
        }
        *(float4*)(C + (size_t)(bm + ty * 4 + i) * ldc + bn + tx * 4) = v;
    }
}

__global__ __launch_bounds__(256) void k_gemm_p(const float* __restrict__ A, const float* __restrict__ B,
                                                float* __restrict__ psum, int Nc, int Ktot, int klen) {
    __shared__ float As[16][64];
    __shared__ float Bs[16][64];
    int tid = threadIdx.x;
    int tx = tid & 15, ty = tid >> 4;
    int bm = blockIdx.x * 64, bn = blockIdx.y * 64;
    int kb = blockIdx.z * klen;
    float acc[4][4] = {{0.f}};
    int am = tid >> 2;
    int ak = (tid & 3) * 4;
    int bk = tid >> 4;
    int bn4 = (tid & 15) * 4;
    const float* Ap = A + (size_t)(bm + am) * Ktot + kb + ak;
    const float* Bp = B + (size_t)(kb + bk) * Nc + bn + bn4;
    float4 av = *(const float4*)Ap;
    float4 bv = *(const float4*)Bp;
    for (int k0 = 0; k0 < klen; k0 += 16) {
        As[ak + 0][am] = av.x;
        As[ak + 1][am] = av.y;
        As[ak + 2][am] = av.z;
        As[ak + 3][am] = av.w;
        *(float4*)&Bs[bk][bn4] = bv;
        __syncthreads();
        if (k0 + 16 < klen) {
            av = *(const float4*)(Ap + k0 + 16);
            bv = *(const float4*)(Bp + (size_t)(k0 + 16) * Nc);
        }
        GEMM_COMPUTE_16()
        __syncthreads();
    }
    float* out = psum + (size_t)blockIdx.z * N_GRAPH * Nc;
#pragma unroll
    for (int i = 0; i < 4; ++i) {
        float4 v = make_float4(acc[i][0], acc[i][1], acc[i][2], acc[i][3]);
        *(float4*)(out + (size_t)(bm + ty * 4 + i) * Nc + bn + tx * 4) = v;
    }
}

__global__ __launch_bounds__(256) void k_reduce(const float* __restrict__ psum, const float* __restrict__ bias,
                                                float* __restrict__ C, int S, int Nc, int ldc, int do_relu) {
    int idx = blockIdx.x * 256 + threadIdx.x;
    int nq = Nc >> 2;
    if (idx >= N_GRAPH * nq) return;
    int m = idx / nq;
    int j = (idx - m * nq) * 4;
    float4 s = *(const float4*)(psum + (size_t)m * Nc + j);
    for (int z = 1; z < S; ++z) {
        float4 t = *(const float4*)(psum + (size_t)z * N_GRAPH * Nc + (size_t)m * Nc + j);
        s.x += t.x; s.y += t.y; s.z += t.z; s.w += t.w;
    }
    float4 bi = *(const float4*)(bias + j);
    s.x += bi.x; s.y += bi.y; s.z += bi.z; s.w += bi.w;
    if (do_relu) {
        s.x = fmaxf(s.x, 0.f); s.y = fmaxf(s.y, 0.f);
        s.z = fmaxf(s.z, 0.f); s.w = fmaxf(s.w, 0.f);
    }
    *(float4*)(C + (size_t)m * ldc + j) = s;
}

// ---------------- final dot ----------------

__global__ __launch_bounds__(256) void k_out(const float* __restrict__ z2, const float* __restrict__ w,
                                             const float* __restrict__ b, float* __restrict__ out) {
    int gid = blockIdx.x * 256 + threadIdx.x;
    int g = gid >> 6;
    int lane = threadIdx.x & 63;
    if (g >= N_GRAPH) return;
    float4 a = *(const float4*)(z2 + (size_t)g * 256 + lane * 4);
    float4 wv = *(const float4*)(w + lane * 4);
    float v = a.x * wv.x + a.y * wv.y + a.z * wv.z + a.w * wv.w;
#pragma unroll
    for (int off = 32; off > 0; off >>= 1) v += __shfl_down(v, off);
    if (lane == 0) out[g] = v + b[0];
}

// ---------------- launcher ----------------

extern "C" void kernel_launch(void* const* d_in, const int* in_sizes, int n_in,
                              void* d_out, int out_size, void* d_ws, size_t ws_size,
                              hipStream_t stream) {
    const float* x     = (const float*)d_in[0];
    const int*   eidx  = (const int*)d_in[1];
    const int*   batch = (const int*)d_in[2];
    const float* sf    = (const float*)d_in[3];
    const float* w1a   = (const float*)d_in[4];
    const float* b1a   = (const float*)d_in[5];
    const float* ws_a  = (const float*)d_in[6];
    const float* bs_a  = (const float*)d_in[7];
    const float* ws_b  = (const float*)d_in[8];
    const float* bs_b  = (const float*)d_in[9];
    const float* bn_g  = (const float*)d_in[10];
    const float* bn_b  = (const float*)d_in[11];
    const float* fcg_w = (const float*)d_in[12];
    const float* fcg_b = (const float*)d_in[13];
    const float* fs1_w = (const float*)d_in[14];
    const float* fs1_b = (const float*)d_in[15];
    const float* fs2_w = (const float*)d_in[16];
    const float* fs2_b = (const float*)d_in[17];
    const float* fc1_w = (const float*)d_in[18];
    const float* fc1_b = (const float*)d_in[19];
    const float* fc2_w = (const float*)d_in[20];
    const float* fc2_b = (const float*)d_in[21];
    const float* out_w = (const float*)d_in[22];
    const float* out_b = (const float*)d_in[23];
    float* dout = (float*)d_out;

    char* p = (char*)d_ws;
    float*  scr     = (float*)p;  p += (size_t)N_NODES * 64 * 4;   // 25.6 MB (CSR ebuf + head alias)
    ushort* u0      = (ushort*)p; p += (size_t)N_NODES * 32 * 2;   // 6.4 MB
    ushort* u1      = (ushort*)p; p += (size_t)N_NODES * 32 * 2;   // 6.4 MB
    int*    ssrc    = (int*)p;    p += (size_t)N_EDGES * 4;        // 6.4 MB
    int*    row_ptr = (int*)p;    p += (size_t)N_NODES * 4;
    int*    row_end = (int*)p;    p += (size_t)N_NODES * 4;
    int*    permb   = (int*)p;    p += (size_t)N_NODES * 4;        // 400 KB degree-sorted perm
    int*    cnt     = (int*)p;    p += (size_t)NTOT * 4;           // 200 KB
    int*    part2   = (int*)p;    p += 512 * 4;
    int*    bstart  = (int*)p;    p += 256 * 4;
    float*  stats   = (float*)p;  p += (size_t)5 * NSLOT * 64 * 4; // 10 KB, zero start
    float*  pooled  = (float*)p;  p += (size_t)N_GRAPH * 32 * 4;   // zero end
    ushort* ybuf    = (ushort*)p; p += (size_t)N_NODES * 32 * 2;   // 6.4 MB (y = x@W1a)

    // CSR bucket buffer aliases scr (dead until head)
    int2* ebuf = (int2*)scr;

    // head buffers alias scr
    float* zcat  = scr;                   // 2048*256   (2 MB)  [gfeat | s2]
    float* z1buf = zcat + 2048 * 256;     // 2048*1024  (8 MB)
    float* z2buf = z1buf + 2048 * 1024;   // 2048*256   (2 MB)
    float* s1buf = z2buf + 2048 * 256;    // 2048*256   (2 MB)
    float* psum  = s1buf + 2048 * 256;    // up to 4*2048*256 (8 MB)

    size_t zero_bytes = ((size_t)5 * NSLOT * 64 + (size_t)N_GRAPH * 32) * 4;
    hipMemsetAsync(stats, 0, zero_bytes, stream);

    const int* esrc = eidx;
    const int* edst = eidx + N_EDGES;

    // ---- CSR build (bucket sort, zero global atomics) + degree-sorted perm ----
    const int scan_blocks = NTOT / 1024;  // 49 (exact)
    k_bcount<<<PART_B, 256, 0, stream>>>(edst, cnt);
    k_scan_partial2<<<scan_blocks, 256, 0, stream>>>(cnt, part2, NTOT);
    k_scan_offsets2<<<1, 256, 0, stream>>>(part2, scan_blocks, bstart);
    k_scan_final2<<<scan_blocks, 256, 0, stream>>>(cnt, part2, bstart, NTOT);
    k_bpart<<<PART_B, 256, 0, stream>>>(esrc, edst, cnt, ebuf);
    k_bfine<<<NB_BUCK, 256, 0, stream>>>(ebuf, bstart, row_ptr, row_end, ssrc, permb);

    const int SLOT_STRIDE = NSLOT * 64;  // 512 floats per layer
    const int nblk4 = (N_NODES * 4 + 255) / 256;  // 1563

    // layer 1: y = x @ W1a (dense), then fused gather(y) + bias/relu + Wb + stats
    k_xw1<<<nblk4, 256, 0, stream>>>(x, w1a, ybuf);
    k_fused1y<<<nblk4, 256, 0, stream>>>(ybuf, row_ptr, row_end, ssrc, permb,
                                         b1a, ws_b, bs_b, u0, stats);

    // layers 2-5 (fused BN+gather + MLP + stats), u double-buffered
    ushort* uin = u0;
    ushort* uout = u1;
    for (int L = 1; L <= 4; ++L) {
        k_fused<<<nblk4, 256, 0, stream>>>(
            uin, uout,
            stats + (size_t)(L - 1) * SLOT_STRIDE, stats + (size_t)L * SLOT_STRIDE,
            bn_g + (L - 1) * 32, bn_b + (L - 1) * 32,
            row_ptr, row_end, ssrc, permb,
            ws_a + (size_t)(L - 1) * 1024, bs_a + (L - 1) * 32,
            ws_b + (size_t)L * 1024, bs_b + L * 32);
        ushort* t = uin; uin = uout; uout = t;
    }
    // uin now holds layer-5 pre-BN output

    // layer-5 BN + pooling
    {
        int waves = (N_NODES + 127) / 128;
        int blocks = (waves + 3) / 4;
        k_bn_pool<<<blocks, 256, 0, stream>>>(uin, stats + (size_t)4 * SLOT_STRIDE,
                                              bn_g + 128, bn_b + 128, batch, pooled);
    }

    // head
    k_gemm_f<<<dim3(32, 2), 256, 0, stream>>>(pooled, fcg_w, fcg_b, zcat, 128, 32, 256, 1);     // gfeat -> z[:, :128]
    k_gemm_p<<<dim3(32, 4, 4), 256, 0, stream>>>(sf, fs1_w, psum, 256, 512, 128);               // fs1 partials
    k_reduce<<<512, 256, 0, stream>>>(psum, fs1_b, s1buf, 4, 256, 256, 1);
    k_gemm_p<<<dim3(32, 2, 4), 256, 0, stream>>>(s1buf, fs2_w, psum, 128, 256, 64);             // fs2 partials
    k_reduce<<<256, 256, 0, stream>>>(psum, fs2_b, zcat + 128, 4, 128, 256, 1);                 // -> z[:, 128:]
    k_gemm_f<<<dim3(32, 16), 256, 0, stream>>>(zcat, fc1_w, fc1_b, z1buf, 1024, 256, 1024, 1);  // fc1
    k_gemm_p<<<dim3(32, 4, 4), 256, 0, stream>>>(z1buf, fc2_w, psum, 256, 1024, 256);           // fc2 partials
    k_reduce<<<512, 256, 0, stream>>>(psum, fc2_b, z2buf, 4, 256, 256, 1);
    k_out<<<512, 256, 0, stream>>>(z2buf, out_w, out_b, dout);
}

// Round 11
// 514.624 us; speedup vs baseline: 1.0722x; 1.0722x over previous
//
#include <hip/hip_runtime.h>
#include <hip/hip_bf16.h>

static constexpr int N_NODES = 100000;
static constexpr int N_EDGES = 1600000;
static constexpr int N_GRAPH = 2048;
static constexpr float BN_EPS_C = 1e-5f;

// bucket-sort CSR build parameters
static constexpr int BUCK_SHIFT = 9;                         // 512 nodes per bucket
static constexpr int NB_BUCK = (N_NODES + 511) >> 9;         // 196
static constexpr int PART_B = 256;                           // partition blocks
static constexpr int CHUNK = N_EDGES / PART_B;               // 6250 (exact)
static constexpr int NTOT = NB_BUCK * PART_B;                // 50176 = 49*1024 (exact)
static constexpr int NSLOT = 8;                              // BN-stats atomic slots

typedef unsigned int uint;
typedef unsigned short ushort;

// ---------------- bf16 helpers (RNE pack, shift unpack) ----------------

__device__ inline uint pk2(float a, float b) {
    uint ua = __float_as_uint(a), ub = __float_as_uint(b);
    ua = (ua + 0x7fffu + ((ua >> 16) & 1u)) >> 16;
    ub = (ub + 0x7fffu + ((ub >> 16) & 1u)) >> 16;
    return ua | (ub << 16);
}
__device__ inline float b2f_lo(uint u) { return __uint_as_float(u << 16); }
__device__ inline float b2f_hi(uint u) { return __uint_as_float(u & 0xffff0000u); }

__device__ inline void unpack8(uint4 v, float* f) {
    f[0] = b2f_lo(v.x); f[1] = b2f_hi(v.x);
    f[2] = b2f_lo(v.y); f[3] = b2f_hi(v.y);
    f[4] = b2f_lo(v.z); f[5] = b2f_hi(v.z);
    f[6] = b2f_lo(v.w); f[7] = b2f_hi(v.w);
}

// ---------------- CSR build: two-level bucket sort, LDS atomics only ----------------

__global__ __launch_bounds__(256) void k_bcount(const int* __restrict__ dst, int* __restrict__ cnt) {
    __shared__ int h[NB_BUCK];
    int blk = blockIdx.x, tid = threadIdx.x;
    for (int i = tid; i < NB_BUCK; i += 256) h[i] = 0;
    __syncthreads();
    int base = blk * CHUNK;
    for (int e = base + tid; e < base + CHUNK; e += 256) {
        int d = __builtin_nontemporal_load(&dst[e]);
        atomicAdd(&h[d >> BUCK_SHIFT], 1);
    }
    __syncthreads();
    for (int i = tid; i < NB_BUCK; i += 256) cnt[i * PART_B + blk] = h[i];
}

__global__ __launch_bounds__(256) void k_scan_partial2(const int* __restrict__ v, int* __restrict__ part, int n) {
    __shared__ int sw[4];
    int b = blockIdx.x, tid = threadIdx.x;
    int base = b * 1024;
    int s = 0;
#pragma unroll
    for (int r = 0; r < 4; ++r) {
        int i = base + r * 256 + tid;
        if (i < n) s += v[i];
    }
#pragma unroll
    for (int off = 32; off > 0; off >>= 1) s += __shfl_down(s, off);
    if ((tid & 63) == 0) sw[tid >> 6] = s;
    __syncthreads();
    if (tid == 0) part[b] = sw[0] + sw[1] + sw[2] + sw[3];
}

__global__ __launch_bounds__(256) void k_scan_offsets2(int* __restrict__ part, int nb, int* __restrict__ bstart) {
    __shared__ int sh[256];
    int tid = threadIdx.x;
    sh[tid] = (tid < nb) ? part[tid] : 0;
    __syncthreads();
    if (tid == 0) {
        int run = 0;
        for (int i = 0; i < nb; ++i) { int v = sh[i]; sh[i] = run; run += v; }
        bstart[NB_BUCK] = run;
    }
    __syncthreads();
    if (tid < nb) part[tid] = sh[tid];
}

__global__ __launch_bounds__(256) void k_scan_final2(int* __restrict__ cnt, const int* __restrict__ part,
                                                     int* __restrict__ bstart, int n) {
    __shared__ int wsum[4];
    int b = blockIdx.x, tid = threadIdx.x;
    int lane = tid & 63, w = tid >> 6;
    int base = b * 1024 + tid * 4;
    int v[4];
#pragma unroll
    for (int r = 0; r < 4; ++r) {
        int i = base + r;
        v[r] = (i < n) ? cnt[i] : 0;
    }
    int tsum = v[0] + v[1] + v[2] + v[3];
    int inc = tsum;
#pragma unroll
    for (int off = 1; off < 64; off <<= 1) {
        int t = __shfl_up(inc, off);
        if (lane >= off) inc += t;
    }
    if (lane == 63) wsum[w] = inc;
    __syncthreads();
    int woff = 0;
    for (int ww = 0; ww < w; ++ww) woff += wsum[ww];
    int run = part[b] + woff + (inc - tsum);
#pragma unroll
    for (int r = 0; r < 4; ++r) {
        int idx = base + r;
        if (idx < n) {
            int c = v[r];
            cnt[idx] = run;
            if ((idx & (PART_B - 1)) == 0) bstart[idx / PART_B] = run;
            run += c;
        }
    }
}

__global__ __launch_bounds__(256) void k_bpart(const int* __restrict__ src, const int* __restrict__ dst,
                                               const int* __restrict__ cnt, int2* __restrict__ ebuf) {
    __shared__ int cur[NB_BUCK];
    int blk = blockIdx.x, tid = threadIdx.x;
    for (int i = tid; i < NB_BUCK; i += 256) cur[i] = cnt[i * PART_B + blk];
    __syncthreads();
    int base = blk * CHUNK;
    for (int e = base + tid; e < base + CHUNK; e += 256) {
        int d = __builtin_nontemporal_load(&dst[e]);
        int s = __builtin_nontemporal_load(&src[e]);
        int p = atomicAdd(&cur[d >> BUCK_SHIFT], 1);
        ebuf[p] = make_int2(d, s);
    }
}

__global__ __launch_bounds__(256) void k_bfine(const int2* __restrict__ ebuf, const int* __restrict__ bstart,
                                               int* __restrict__ row_ptr, int* __restrict__ row_end,
                                               int* __restrict__ ssrc) {
    __shared__ int fh[512];
    __shared__ int wsum[4];
    int b = blockIdx.x, tid = threadIdx.x;
    int n0 = b << BUCK_SHIFT;
    int e0 = bstart[b], e1 = bstart[b + 1];
    fh[tid] = 0; fh[tid + 256] = 0;
    __syncthreads();
    for (int e = e0 + tid; e < e1; e += 256)
        atomicAdd(&fh[ebuf[e].x - n0], 1);
    __syncthreads();
    int a0 = fh[2 * tid], a1 = fh[2 * tid + 1];
    int s = a0 + a1;
    int lane = tid & 63, w = tid >> 6;
    int inc = s;
#pragma unroll
    for (int off = 1; off < 64; off <<= 1) {
        int t = __shfl_up(inc, off);
        if (lane >= off) inc += t;
    }
    if (lane == 63) wsum[w] = inc;
    __syncthreads();
    int woff = 0;
    for (int ww = 0; ww < w; ++ww) woff += wsum[ww];
    int excl = woff + inc - s;
    int p0 = excl, p1 = excl + a0;
    int node0 = n0 + 2 * tid, node1 = node0 + 1;
    if (node0 < N_NODES) { row_ptr[node0] = e0 + p0; row_end[node0] = e0 + p0 + a0; }
    if (node1 < N_NODES) { row_ptr[node1] = e0 + p1; row_end[node1] = e0 + p1 + a1; }
    fh[2 * tid] = p0; fh[2 * tid + 1] = p1;
    __syncthreads();
    for (int e = e0 + tid; e < e1; e += 256) {
        int2 v = ebuf[e];
        int p = atomicAdd(&fh[v.x - n0], 1);
        ssrc[e0 + p] = v.y;
    }
}

// ---------------- layer-1 weight commute: y = x @ W1a ----------------

__global__ __launch_bounds__(256) void k_xw1(const float* __restrict__ x, const float* __restrict__ Wa,
                                             ushort* __restrict__ y) {
    __shared__ float sWa[2048];   // 64x32, col XOR-swizzled by ((r>>4)&3)<<2
    int tid = threadIdx.x;
    for (int i = tid; i < 2048; i += 256) {
        int r = i >> 5, c = i & 31;
        sWa[(r << 5) + (c ^ (((r >> 4) & 3) << 2))] = Wa[i];
    }
    __syncthreads();
    int idx = blockIdx.x * 256 + tid;
    int node = idx >> 2;
    int sl = idx & 3;
    int k0 = sl * 16;
    bool active = node < N_NODES;

    float xv[16];
    if (active) {
        const float* xr = x + (size_t)node * 64 + k0;
        *(float4*)(xv + 0)  = *(const float4*)(xr + 0);
        *(float4*)(xv + 4)  = *(const float4*)(xr + 4);
        *(float4*)(xv + 8)  = *(const float4*)(xr + 8);
        *(float4*)(xv + 12) = *(const float4*)(xr + 12);
    } else {
#pragma unroll
        for (int j = 0; j < 16; ++j) xv[j] = 0.f;
    }

    float pj[32];
#pragma unroll
    for (int j = 0; j < 32; ++j) pj[j] = 0.f;
    int sw = sl << 2;
#pragma unroll
    for (int kk = 0; kk < 16; ++kk) {
        float a = xv[kk];
        const float* rb = sWa + ((k0 + kk) << 5);
#pragma unroll
        for (int j4 = 0; j4 < 8; ++j4) {
            int jo = j4 << 2;
            float4 wv = *(const float4*)(rb + (jo ^ sw));
            pj[jo + 0] = fmaf(a, wv.x, pj[jo + 0]);
            pj[jo + 1] = fmaf(a, wv.y, pj[jo + 1]);
            pj[jo + 2] = fmaf(a, wv.z, pj[jo + 2]);
            pj[jo + 3] = fmaf(a, wv.w, pj[jo + 3]);
        }
    }
#pragma unroll
    for (int j = 0; j < 32; ++j) {
        pj[j] += __shfl_xor(pj[j], 1);
        pj[j] += __shfl_xor(pj[j], 2);
    }
    if (active && sl == 0) {
        uint pk[16];
#pragma unroll
        for (int j = 0; j < 16; ++j) pk[j] = pk2(pj[2 * j], pj[2 * j + 1]);
        uint4* yp = (uint4*)(y + (size_t)node * 32);
        yp[0] = make_uint4(pk[0], pk[1], pk[2], pk[3]);
        yp[1] = make_uint4(pk[4], pk[5], pk[6], pk[7]);
        yp[2] = make_uint4(pk[8], pk[9], pk[10], pk[11]);
        yp[3] = make_uint4(pk[12], pk[13], pk[14], pk[15]);
    }
}

// ---------------- fused layer 1: gather(y) + bias/relu + Wb GEMM + BN-stats ----------------
// 4 lanes/node, unroll-8 edge pipeline (8 row loads in flight).

__global__ __launch_bounds__(256) void k_fused1y(const ushort* __restrict__ y,
                                                 const int* __restrict__ row_ptr, const int* __restrict__ row_end,
                                                 const int* __restrict__ ssrc,
                                                 const float* __restrict__ ba,
                                                 const float* __restrict__ Wb, const float* __restrict__ bb,
                                                 ushort* __restrict__ uout, float* __restrict__ stats_out) {
    __shared__ float sWb[1024];
    __shared__ float sba[32];
    __shared__ float sbb[32];
    __shared__ float bstats[64];
    __shared__ float tile[64][36];
    int tid = threadIdx.x;
    for (int i = tid; i < 1024; i += 256) sWb[i] = Wb[i];
    if (tid < 32) { sba[tid] = ba[tid]; sbb[tid] = bb[tid]; }
    if (tid < 64) bstats[tid] = 0.f;
    __syncthreads();

    int idx = blockIdx.x * 256 + tid;
    int node = idx >> 2;
    int sl = idx & 3;
    int f8 = sl * 8;
    int nloc = tid >> 2;
    bool active = node < N_NODES;

    float acc[8] = {0.f, 0.f, 0.f, 0.f, 0.f, 0.f, 0.f, 0.f};
    if (active) {
        unpack8(*(const uint4*)(y + (size_t)node * 32 + f8), acc);
        int e = row_ptr[node], e1 = row_end[node];
        float v[8];
        for (; e + 8 <= e1; e += 8) {
            int si[8];
#pragma unroll
            for (int q = 0; q < 8; ++q) si[q] = ssrc[e + q];
            uint4 rv[8];
#pragma unroll
            for (int q = 0; q < 8; ++q) rv[q] = *(const uint4*)(y + (size_t)si[q] * 32 + f8);
#pragma unroll
            for (int q = 0; q < 8; ++q) {
                unpack8(rv[q], v);
#pragma unroll
                for (int j = 0; j < 8; ++j) acc[j] += v[j];
            }
        }
        for (; e + 4 <= e1; e += 4) {
            int s0 = ssrc[e], s1 = ssrc[e + 1], s2 = ssrc[e + 2], s3 = ssrc[e + 3];
            uint4 va = *(const uint4*)(y + (size_t)s0 * 32 + f8);
            uint4 vb = *(const uint4*)(y + (size_t)s1 * 32 + f8);
            uint4 vc = *(const uint4*)(y + (size_t)s2 * 32 + f8);
            uint4 vd = *(const uint4*)(y + (size_t)s3 * 32 + f8);
            unpack8(va, v);
#pragma unroll
            for (int j = 0; j < 8; ++j) acc[j] += v[j];
            unpack8(vb, v);
#pragma unroll
            for (int j = 0; j < 8; ++j) acc[j] += v[j];
            unpack8(vc, v);
#pragma unroll
            for (int j = 0; j < 8; ++j) acc[j] += v[j];
            unpack8(vd, v);
#pragma unroll
            for (int j = 0; j < 8; ++j) acc[j] += v[j];
        }
        for (; e < e1; ++e) {
            int s = ssrc[e];
            unpack8(*(const uint4*)(y + (size_t)s * 32 + f8), v);
#pragma unroll
            for (int j = 0; j < 8; ++j) acc[j] += v[j];
        }
    }

    float h8[8];
#pragma unroll
    for (int j = 0; j < 8; ++j) h8[j] = fmaxf(acc[j] + sba[f8 + j], 0.f);
    *(float4*)&tile[nloc][f8] = make_float4(h8[0], h8[1], h8[2], h8[3]);
    *(float4*)&tile[nloc][f8 + 4] = make_float4(h8[4], h8[5], h8[6], h8[7]);
    __syncthreads();

    float uu[8];
#pragma unroll
    for (int j = 0; j < 8; ++j) uu[j] = sbb[f8 + j];
#pragma unroll
    for (int k4 = 0; k4 < 8; ++k4) {
        float4 hv = *(const float4*)&tile[nloc][k4 * 4];
        float hvv[4] = {hv.x, hv.y, hv.z, hv.w};
#pragma unroll
        for (int m = 0; m < 4; ++m) {
            int k = k4 * 4 + m;
            float a = hvv[m];
            const float4* wr = (const float4*)(sWb + k * 32 + f8);
            float4 w0 = wr[0], w1 = wr[1];
            uu[0] = fmaf(a, w0.x, uu[0]);
            uu[1] = fmaf(a, w0.y, uu[1]);
            uu[2] = fmaf(a, w0.z, uu[2]);
            uu[3] = fmaf(a, w0.w, uu[3]);
            uu[4] = fmaf(a, w1.x, uu[4]);
            uu[5] = fmaf(a, w1.y, uu[5]);
            uu[6] = fmaf(a, w1.z, uu[6]);
            uu[7] = fmaf(a, w1.w, uu[7]);
        }
    }

    if (active) {
        uint4 pkv = make_uint4(pk2(uu[0], uu[1]), pk2(uu[2], uu[3]), pk2(uu[4], uu[5]), pk2(uu[6], uu[7]));
        *(uint4*)(uout + (size_t)node * 32 + f8) = pkv;
    } else {
#pragma unroll
        for (int j = 0; j < 8; ++j) uu[j] = 0.f;
    }

#pragma unroll
    for (int j = 0; j < 8; ++j) {
        float v = uu[j];
        float v2 = v * v;
        v += __shfl_xor(v, 4);  v2 += __shfl_xor(v2, 4);
        v += __shfl_xor(v, 8);  v2 += __shfl_xor(v2, 8);
        v += __shfl_xor(v, 16); v2 += __shfl_xor(v2, 16);
        v += __shfl_xor(v, 32); v2 += __shfl_xor(v2, 32);
        if ((tid & 63) < 4) {
            atomicAdd(&bstats[f8 + j], v);
            atomicAdd(&bstats[32 + f8 + j], v2);
        }
    }
    __syncthreads();
    if (tid < 64) atomicAdd(&stats_out[(blockIdx.x & (NSLOT - 1)) * 64 + tid], bstats[tid]);
}

// ---------------- fused layers 2-5: BN+gather(u) + MLP + BN-stats ----------------
// 4 lanes/node, unroll-8 edge pipeline.

__global__ __launch_bounds__(256) void k_fused(const ushort* __restrict__ uin, ushort* __restrict__ uout,
                                               const float* __restrict__ stats_in, float* __restrict__ stats_out,
                                               const float* __restrict__ bng, const float* __restrict__ bnb,
                                               const int* __restrict__ row_ptr, const int* __restrict__ row_end,
                                               const int* __restrict__ ssrc,
                                               const float* __restrict__ Wa, const float* __restrict__ ba,
                                               const float* __restrict__ Wb, const float* __restrict__ bb) {
    __shared__ float sWa[1024];   // 32x32, col XOR-swizzled by ((r>>3)&3)<<2
    __shared__ float sWb[1024];
    __shared__ float sba[32];
    __shared__ float sbb[32];
    __shared__ float bstats[64];
    int tid = threadIdx.x;
    for (int i = tid; i < 1024; i += 256) {
        int r = i >> 5, c = i & 31;
        sWa[(r << 5) + (c ^ (((r >> 3) & 3) << 2))] = Wa[i];
        sWb[i] = Wb[i];
    }
    if (tid < 32) { sba[tid] = ba[tid]; sbb[tid] = bb[tid]; }
    if (tid < 64) bstats[tid] = 0.f;
    __syncthreads();

    int idx = blockIdx.x * 256 + tid;
    int node = idx >> 2;
    int sl = idx & 3;
    int f8 = sl * 8;
    bool active = node < N_NODES;

    const float inv = 1.0f / (float)N_NODES;
    float sc[8], sh[8];
    {
        float s1[8] = {0,0,0,0,0,0,0,0}, s2[8] = {0,0,0,0,0,0,0,0};
        for (int s = 0; s < NSLOT; ++s) {
            const float* sp = stats_in + s * 64;
            float4 a = *(const float4*)(sp + f8);
            float4 b = *(const float4*)(sp + f8 + 4);
            float4 c = *(const float4*)(sp + 32 + f8);
            float4 d = *(const float4*)(sp + 36 + f8);
            s1[0] += a.x; s1[1] += a.y; s1[2] += a.z; s1[3] += a.w;
            s1[4] += b.x; s1[5] += b.y; s1[6] += b.z; s1[7] += b.w;
            s2[0] += c.x; s2[1] += c.y; s2[2] += c.z; s2[3] += c.w;
            s2[4] += d.x; s2[5] += d.y; s2[6] += d.z; s2[7] += d.w;
        }
        float g[8], b[8];
        *(float4*)g = *(const float4*)(bng + f8); *(float4*)(g + 4) = *(const float4*)(bng + f8 + 4);
        *(float4*)b = *(const float4*)(bnb + f8); *(float4*)(b + 4) = *(const float4*)(bnb + f8 + 4);
#pragma unroll
        for (int j = 0; j < 8; ++j) {
            float mu = s1[j] * inv;
            sc[j] = rsqrtf(s2[j] * inv - mu * mu + BN_EPS_C) * g[j];
            sh[j] = b[j] - mu * sc[j];
        }
    }

    float acc[8] = {0.f, 0.f, 0.f, 0.f, 0.f, 0.f, 0.f, 0.f};
    if (active) {
        float v[8];
        unpack8(*(const uint4*)(uin + (size_t)node * 32 + f8), v);
#pragma unroll
        for (int j = 0; j < 8; ++j) acc[j] = fmaxf(fmaf(v[j], sc[j], sh[j]), 0.f);
        int e = row_ptr[node], e1 = row_end[node];
        for (; e + 8 <= e1; e += 8) {
            int si[8];
#pragma unroll
            for (int q = 0; q < 8; ++q) si[q] = ssrc[e + q];
            uint4 rv[8];
#pragma unroll
            for (int q = 0; q < 8; ++q) rv[q] = *(const uint4*)(uin + (size_t)si[q] * 32 + f8);
#pragma unroll
            for (int q = 0; q < 8; ++q) {
                unpack8(rv[q], v);
#pragma unroll
                for (int j = 0; j < 8; ++j) acc[j] += fmaxf(fmaf(v[j], sc[j], sh[j]), 0.f);
            }
        }
        for (; e + 4 <= e1; e += 4) {
            int s0 = ssrc[e], s1 = ssrc[e + 1], s2 = ssrc[e + 2], s3 = ssrc[e + 3];
            uint4 va = *(const uint4*)(uin + (size_t)s0 * 32 + f8);
            uint4 vb = *(const uint4*)(uin + (size_t)s1 * 32 + f8);
            uint4 vc = *(const uint4*)(uin + (size_t)s2 * 32 + f8);
            uint4 vd = *(const uint4*)(uin + (size_t)s3 * 32 + f8);
            unpack8(va, v);
#pragma unroll
            for (int j = 0; j < 8; ++j) acc[j] += fmaxf(fmaf(v[j], sc[j], sh[j]), 0.f);
            unpack8(vb, v);
#pragma unroll
            for (int j = 0; j < 8; ++j) acc[j] += fmaxf(fmaf(v[j], sc[j], sh[j]), 0.f);
            unpack8(vc, v);
#pragma unroll
            for (int j = 0; j < 8; ++j) acc[j] += fmaxf(fmaf(v[j], sc[j], sh[j]), 0.f);
            unpack8(vd, v);
#pragma unroll
            for (int j = 0; j < 8; ++j) acc[j] += fmaxf(fmaf(v[j], sc[j], sh[j]), 0.f);
        }
        for (; e < e1; ++e) {
            int s = ssrc[e];
            unpack8(*(const uint4*)(uin + (size_t)s * 32 + f8), v);
#pragma unroll
            for (int j = 0; j < 8; ++j) acc[j] += fmaxf(fmaf(v[j], sc[j], sh[j]), 0.f);
        }
    }

    // phase 1 partials; read at (jo^sw), accumulate at original column jo
    float pj[32];
#pragma unroll
    for (int j = 0; j < 32; ++j) pj[j] = 0.f;
    int sw = sl << 2;
#pragma unroll
    for (int kk = 0; kk < 8; ++kk) {
        float a = acc[kk];
        const float* rb = sWa + ((f8 + kk) << 5);
#pragma unroll
        for (int j4 = 0; j4 < 8; ++j4) {
            int jo = j4 << 2;
            float4 wv = *(const float4*)(rb + (jo ^ sw));
            pj[jo + 0] = fmaf(a, wv.x, pj[jo + 0]);
            pj[jo + 1] = fmaf(a, wv.y, pj[jo + 1]);
            pj[jo + 2] = fmaf(a, wv.z, pj[jo + 2]);
            pj[jo + 3] = fmaf(a, wv.w, pj[jo + 3]);
        }
    }
#pragma unroll
    for (int j = 0; j < 32; ++j) {
        pj[j] += __shfl_xor(pj[j], 1);
        pj[j] += __shfl_xor(pj[j], 2);
        pj[j] = fmaxf(pj[j] + sba[j], 0.f);
    }

    float uu[8];
#pragma unroll
    for (int j = 0; j < 8; ++j) uu[j] = sbb[f8 + j];
#pragma unroll
    for (int k = 0; k < 32; ++k) {
        float a = pj[k];
        const float4* wr = (const float4*)(sWb + k * 32 + f8);
        float4 w0 = wr[0], w1 = wr[1];
        uu[0] = fmaf(a, w0.x, uu[0]);
        uu[1] = fmaf(a, w0.y, uu[1]);
        uu[2] = fmaf(a, w0.z, uu[2]);
        uu[3] = fmaf(a, w0.w, uu[3]);
        uu[4] = fmaf(a, w1.x, uu[4]);
        uu[5] = fmaf(a, w1.y, uu[5]);
        uu[6] = fmaf(a, w1.z, uu[6]);
        uu[7] = fmaf(a, w1.w, uu[7]);
    }

    if (active) {
        uint4 pkv = make_uint4(pk2(uu[0], uu[1]), pk2(uu[2], uu[3]), pk2(uu[4], uu[5]), pk2(uu[6], uu[7]));
        *(uint4*)(uout + (size_t)node * 32 + f8) = pkv;
    } else {
#pragma unroll
        for (int j = 0; j < 8; ++j) uu[j] = 0.f;
    }

#pragma unroll
    for (int j = 0; j < 8; ++j) {
        float v = uu[j];
        float v2 = v * v;
        v += __shfl_xor(v, 4);  v2 += __shfl_xor(v2, 4);
        v += __shfl_xor(v, 8);  v2 += __shfl_xor(v2, 8);
        v += __shfl_xor(v, 16); v2 += __shfl_xor(v2, 16);
        v += __shfl_xor(v, 32); v2 += __shfl_xor(v2, 32);
        if ((tid & 63) < 4) {
            atomicAdd(&bstats[f8 + j], v);
            atomicAdd(&bstats[32 + f8 + j], v2);
        }
    }
    __syncthreads();
    if (tid < 64) atomicAdd(&stats_out[(blockIdx.x & (NSLOT - 1)) * 64 + tid], bstats[tid]);
}

// ---------------- layer-5 BN + graph pooling (segmented over sorted batch) ----------------

__global__ __launch_bounds__(256) void k_bn_pool(const ushort* __restrict__ u, const float* __restrict__ stats,
                                                 const float* __restrict__ bng, const float* __restrict__ bnb,
                                                 const int* __restrict__ batch, float* __restrict__ pooled) {
    const int CH = 128;
    int wid = (blockIdx.x * 256 + threadIdx.x) >> 6;
    int lane = threadIdx.x & 63;
    int f = lane & 31, par = lane >> 5;
    int n0 = wid * CH;
    if (n0 >= N_NODES) return;
    int n1 = n0 + CH; if (n1 > N_NODES) n1 = N_NODES;
    const float inv = 1.0f / (float)N_NODES;
    float sv = 0.f, sq = 0.f;
    for (int s = 0; s < NSLOT; ++s) { sv += stats[s * 64 + f]; sq += stats[s * 64 + 32 + f]; }
    float mu = sv * inv;
    float var = sq * inv - mu * mu;
    float sc = rsqrtf(var + BN_EPS_C) * bng[f];
    float sh = bnb[f] - mu * sc;
    float acc = 0.f;
    int curg = -1;
    for (int n = n0 + par; n < n1; n += 2) {
        int g = batch[n];
        if (g != curg) {
            if (curg >= 0) atomicAdd(&pooled[(size_t)curg * 32 + f], acc);
            acc = 0.f; curg = g;
        }
        float v = b2f_lo((uint)u[(size_t)n * 32 + f]);
        acc += fmaxf(fmaf(v, sc, sh), 0.f);
    }
    if (curg >= 0) atomicAdd(&pooled[(size_t)curg * 32 + f], acc);
}

// ---------------- head GEMMs ----------------

#define GEMM_COMPUTE_16()                                                      \
    _Pragma("unroll")                                                          \
    for (int k = 0; k < 16; ++k) {                                             \
        float4 a4 = *(const float4*)&As[k][ty * 4];                            \
        float4 b4 = *(const float4*)&Bs[k][tx * 4];                            \
        acc[0][0] = fmaf(a4.x, b4.x, acc[0][0]);                               \
        acc[0][1] = fmaf(a4.x, b4.y, acc[0][1]);                               \
        acc[0][2] = fmaf(a4.x, b4.z, acc[0][2]);                               \
        acc[0][3] = fmaf(a4.x, b4.w, acc[0][3]);                               \
        acc[1][0] = fmaf(a4.y, b4.x, acc[1][0]);                               \
        acc[1][1] = fmaf(a4.y, b4.y, acc[1][1]);                               \
        acc[1][2] = fmaf(a4.y, b4.z, acc[1][2]);                               \
        acc[1][3] = fmaf(a4.y, b4.w, acc[1][3]);                               \
        acc[2][0] = fmaf(a4.z, b4.x, acc[2][0]);                               \
        acc[2][1] = fmaf(a4.z, b4.y, acc[2][1]);                               \
        acc[2][2] = fmaf(a4.z, b4.z, acc[2][2]);                               \
        acc[2][3] = fmaf(a4.z, b4.w, acc[2][3]);                               \
        acc[3][0] = fmaf(a4.w, b4.x, acc[3][0]);                               \
        acc[3][1] = fmaf(a4.w, b4.y, acc[3][1]);                               \
        acc[3][2] = fmaf(a4.w, b4.z, acc[3][2]);                               \
        acc[3][3] = fmaf(a4.w, b4.w, acc[3][3]);                               \
    }

__global__ __launch_bounds__(256) void k_gemm_f(const float* __restrict__ A, const float* __restrict__ B,
                                                const float* __restrict__ bias, float* __restrict__ C,
                                                int Nc, int K, int ldc, int do_relu) {
    __shared__ float As[16][64];
    __shared__ float Bs[16][64];
    int tid = threadIdx.x;
    int tx = tid & 15, ty = tid >> 4;
    int bm = blockIdx.x * 64, bn = blockIdx.y * 64;
    float acc[4][4] = {{0.f}};
    int am = tid >> 2;
    int ak = (tid & 3) * 4;
    int bk = tid >> 4;
    int bn4 = (tid & 15) * 4;
    const float* Ap = A + (size_t)(bm + am) * K + ak;
    const float* Bp = B + (size_t)bk * Nc + bn + bn4;
    float4 av = *(const float4*)Ap;
    float4 bv = *(const float4*)Bp;
    for (int k0 = 0; k0 < K; k0 += 16) {
        As[ak + 0][am] = av.x;
        As[ak + 1][am] = av.y;
        As[ak + 2][am] = av.z;
        As[ak + 3][am] = av.w;
        *(float4*)&Bs[bk][bn4] = bv;
        __syncthreads();
        if (k0 + 16 < K) {
            av = *(const float4*)(Ap + k0 + 16);
            bv = *(const float4*)(Bp + (size_t)(k0 + 16) * Nc);
        }
        GEMM_COMPUTE_16()
        __syncthreads();
    }
    float4 bi = *(const float4*)(bias + bn + tx * 4);
#pragma unroll
    for (int i = 0; i < 4; ++i) {
        float4 v;
        v.x = acc[i][0] + bi.x;
        v.y = acc[i][1] + bi.y;
        v.z = acc[i][2] + bi.z;
        v.w = acc[i][3] + bi.w;
        if (do_relu) {
            v.x = fmaxf(v.x, 0.f); v.y = fmaxf(v.y, 0.f);
            v.z = fmaxf(v.z, 0.f); v.w = fmaxf(v.w, 0.f);
        }
        *(float4*)(C + (size_t)(bm + ty * 4 + i) * ldc + bn + tx * 4) = v;
    }
}

__global__ __launch_bounds__(256) void k_gemm_p(const float* __restrict__ A, const float* __restrict__ B,
                                                float* __restrict__ psum, int Nc, int Ktot, int klen) {
    __shared__ float As[16][64];
    __shared__ float Bs[16][64];
    int tid = threadIdx.x;
    int tx = tid & 15, ty = tid >> 4;
    int bm = blockIdx.x * 64, bn = blockIdx.y * 64;
    int kb = blockIdx.z * klen;
    float acc[4][4] = {{0.f}};
    int am = tid >> 2;
    int ak = (tid & 3) * 4;
    int bk = tid >> 4;
    int bn4 = (tid & 15) * 4;
    const float* Ap = A + (size_t)(bm + am) * Ktot + kb + ak;
    const float* Bp = B + (size_t)(kb + bk) * Nc + bn + bn4;
    float4 av = *(const float4*)Ap;
    float4 bv = *(const float4*)Bp;
    for (int k0 = 0; k0 < klen; k0 += 16) {
        As[ak + 0][am] = av.x;
        As[ak + 1][am] = av.y;
        As[ak + 2][am] = av.z;
        As[ak + 3][am] = av.w;
        *(float4*)&Bs[bk][bn4] = bv;
        __syncthreads();
        if (k0 + 16 < klen) {
            av = *(const float4*)(Ap + k0 + 16);
            bv = *(const float4*)(Bp + (size_t)(k0 + 16) * Nc);
        }
        GEMM_COMPUTE_16()
        __syncthreads();
    }
    float* out = psum + (size_t)blockIdx.z * N_GRAPH * Nc;
#pragma unroll
    for (int i = 0; i < 4; ++i) {
        float4 v = make_float4(acc[i][0], acc[i][1], acc[i][2], acc[i][3]);
        *(float4*)(out + (size_t)(bm + ty * 4 + i) * Nc + bn + tx * 4) = v;
    }
}

__global__ __launch_bounds__(256) void k_reduce(const float* __restrict__ psum, const float* __restrict__ bias,
                                                float* __restrict__ C, int S, int Nc, int ldc, int do_relu) {
    int idx = blockIdx.x * 256 + threadIdx.x;
    int nq = Nc >> 2;
    if (idx >= N_GRAPH * nq) return;
    int m = idx / nq;
    int j = (idx - m * nq) * 4;
    float4 s = *(const float4*)(psum + (size_t)m * Nc + j);
    for (int z = 1; z < S; ++z) {
        float4 t = *(const float4*)(psum + (size_t)z * N_GRAPH * Nc + (size_t)m * Nc + j);
        s.x += t.x; s.y += t.y; s.z += t.z; s.w += t.w;
    }
    float4 bi = *(const float4*)(bias + j);
    s.x += bi.x; s.y += bi.y; s.z += bi.z; s.w += bi.w;
    if (do_relu) {
        s.x = fmaxf(s.x, 0.f); s.y = fmaxf(s.y, 0.f);
        s.z = fmaxf(s.z, 0.f); s.w = fmaxf(s.w, 0.f);
    }
    *(float4*)(C + (size_t)m * ldc + j) = s;
}

// ---------------- final dot ----------------

__global__ __launch_bounds__(256) void k_out(const float* __restrict__ z2, const float* __restrict__ w,
                                             const float* __restrict__ b, float* __restrict__ out) {
    int gid = blockIdx.x * 256 + threadIdx.x;
    int g = gid >> 6;
    int lane = threadIdx.x & 63;
    if (g >= N_GRAPH) return;
    float4 a = *(const float4*)(z2 + (size_t)g * 256 + lane * 4);
    float4 wv = *(const float4*)(w + lane * 4);
    float v = a.x * wv.x + a.y * wv.y + a.z * wv.z + a.w * wv.w;
#pragma unroll
    for (int off = 32; off > 0; off >>= 1) v += __shfl_down(v, off);
    if (lane == 0) out[g] = v + b[0];
}

// ---------------- launcher ----------------

extern "C" void kernel_launch(void* const* d_in, const int* in_sizes, int n_in,
                              void* d_out, int out_size, void* d_ws, size_t ws_size,
                              hipStream_t stream) {
    const float* x     = (const float*)d_in[0];
    const int*   eidx  = (const int*)d_in[1];
    const int*   batch = (const int*)d_in[2];
    const float* sf    = (const float*)d_in[3];
    const float* w1a   = (const float*)d_in[4];
    const float* b1a   = (const float*)d_in[5];
    const float* ws_a  = (const float*)d_in[6];
    const float* bs_a  = (const float*)d_in[7];
    const float* ws_b  = (const float*)d_in[8];
    const float* bs_b  = (const float*)d_in[9];
    const float* bn_g  = (const float*)d_in[10];
    const float* bn_b  = (const float*)d_in[11];
    const float* fcg_w = (const float*)d_in[12];
    const float* fcg_b = (const float*)d_in[13];
    const float* fs1_w = (const float*)d_in[14];
    const float* fs1_b = (const float*)d_in[15];
    const float* fs2_w = (const float*)d_in[16];
    const float* fs2_b = (const float*)d_in[17];
    const float* fc1_w = (const float*)d_in[18];
    const float* fc1_b = (const float*)d_in[19];
    const float* fc2_w = (const float*)d_in[20];
    const float* fc2_b = (const float*)d_in[21];
    const float* out_w = (const float*)d_in[22];
    const float* out_b = (const float*)d_in[23];
    float* dout = (float*)d_out;

    char* p = (char*)d_ws;
    float*  scr     = (float*)p;  p += (size_t)N_NODES * 64 * 4;   // 25.6 MB (CSR ebuf + head alias)
    ushort* u0      = (ushort*)p; p += (size_t)N_NODES * 32 * 2;   // 6.4 MB
    ushort* u1      = (ushort*)p; p += (size_t)N_NODES * 32 * 2;   // 6.4 MB
    int*    ssrc    = (int*)p;    p += (size_t)N_EDGES * 4;        // 6.4 MB
    int*    row_ptr = (int*)p;    p += (size_t)N_NODES * 4;
    int*    row_end = (int*)p;    p += (size_t)N_NODES * 4;
    int*    cnt     = (int*)p;    p += (size_t)NTOT * 4;           // 200 KB
    int*    part2   = (int*)p;    p += 512 * 4;
    int*    bstart  = (int*)p;    p += 256 * 4;
    float*  stats   = (float*)p;  p += (size_t)5 * NSLOT * 64 * 4; // 10 KB, zero start
    float*  pooled  = (float*)p;  p += (size_t)N_GRAPH * 32 * 4;   // zero end
    ushort* ybuf    = (ushort*)p; p += (size_t)N_NODES * 32 * 2;   // 6.4 MB (y = x@W1a)

    // CSR bucket buffer aliases scr (dead until head)
    int2* ebuf = (int2*)scr;

    // head buffers alias scr
    float* zcat  = scr;                   // 2048*256   (2 MB)  [gfeat | s2]
    float* z1buf = zcat + 2048 * 256;     // 2048*1024  (8 MB)
    float* z2buf = z1buf + 2048 * 1024;   // 2048*256   (2 MB)
    float* s1buf = z2buf + 2048 * 256;    // 2048*256   (2 MB)
    float* psum  = s1buf + 2048 * 256;    // up to 4*2048*256 (8 MB)

    size_t zero_bytes = ((size_t)5 * NSLOT * 64 + (size_t)N_GRAPH * 32) * 4;
    hipMemsetAsync(stats, 0, zero_bytes, stream);

    const int* esrc = eidx;
    const int* edst = eidx + N_EDGES;

    // ---- CSR build (bucket sort, zero global atomics) ----
    const int scan_blocks = NTOT / 1024;  // 49 (exact)
    k_bcount<<<PART_B, 256, 0, stream>>>(edst, cnt);
    k_scan_partial2<<<scan_blocks, 256, 0, stream>>>(cnt, part2, NTOT);
    k_scan_offsets2<<<1, 256, 0, stream>>>(part2, scan_blocks, bstart);
    k_scan_final2<<<scan_blocks, 256, 0, stream>>>(cnt, part2, bstart, NTOT);
    k_bpart<<<PART_B, 256, 0, stream>>>(esrc, edst, cnt, ebuf);
    k_bfine<<<NB_BUCK, 256, 0, stream>>>(ebuf, bstart, row_ptr, row_end, ssrc);

    const int SLOT_STRIDE = NSLOT * 64;  // 512 floats per layer
    const int nblk4 = (N_NODES * 4 + 255) / 256;  // 1563

    // layer 1: y = x @ W1a (dense), then fused gather(y) + bias/relu + Wb + stats
    k_xw1<<<nblk4, 256, 0, stream>>>(x, w1a, ybuf);
    k_fused1y<<<nblk4, 256, 0, stream>>>(ybuf, row_ptr, row_end, ssrc,
                                         b1a, ws_b, bs_b, u0, stats);

    // layers 2-5 (fused BN+gather + MLP + stats), u double-buffered
    ushort* uin = u0;
    ushort* uout = u1;
    for (int L = 1; L <= 4; ++L) {
        k_fused<<<nblk4, 256, 0, stream>>>(
            uin, uout,
            stats + (size_t)(L - 1) * SLOT_STRIDE, stats + (size_t)L * SLOT_STRIDE,
            bn_g + (L - 1) * 32, bn_b + (L - 1) * 32,
            row_ptr, row_end, ssrc,
            ws_a + (size_t)(L - 1) * 1024, bs_a + (L - 1) * 32,
            ws_b + (size_t)L * 1024, bs_b + L * 32);
        ushort* t = uin; uin = uout; uout = t;
    }
    // uin now holds layer-5 pre-BN output

    // layer-5 BN + pooling
    {
        int waves = (N_NODES + 127) / 128;
        int blocks = (waves + 3) / 4;
        k_bn_pool<<<blocks, 256, 0, stream>>>(uin, stats + (size_t)4 * SLOT_STRIDE,
                                              bn_g + 128, bn_b + 128, batch, pooled);
    }

    // head
    k_gemm_f<<<dim3(32, 2), 256, 0, stream>>>(pooled, fcg_w, fcg_b, zcat, 128, 32, 256, 1);     // gfeat -> z[:, :128]
    k_gemm_p<<<dim3(32, 4, 4), 256, 0, stream>>>(sf, fs1_w, psum, 256, 512, 128);               // fs1 partials
    k_reduce<<<512, 256, 0, stream>>>(psum, fs1_b, s1buf, 4, 256, 256, 1);
    k_gemm_p<<<dim3(32, 2, 4), 256, 0, stream>>>(s1buf, fs2_w, psum, 128, 256, 64);             // fs2 partials
    k_reduce<<<256, 256, 0, stream>>>(psum, fs2_b, zcat + 128, 4, 128, 256, 1);                 // -> z[:, 128:]
    k_gemm_f<<<dim3(32, 16), 256, 0, stream>>>(zcat, fc1_w, fc1_b, z1buf, 1024, 256, 1024, 1);  // fc1
    k_gemm_p<<<dim3(32, 4, 4), 256, 0, stream>>>(z1buf, fc2_w, psum, 256, 1024, 256);           // fc2 partials
    k_reduce<<<512, 256, 0, stream>>>(psum, fc2_b, z2buf, 4, 256, 256, 1);
    k_out<<<512, 256, 0, stream>>>(z2buf, out_w, out_b, dout);
}